// Round 4
// baseline (499.800 us; speedup 1.0000x reference)
//
#include <hip/hip_runtime.h>
#include <hip/hip_bf16.h>
#include <stdint.h>

// Problem constants (IMAGE_SIZES is compile-time constant in the reference)
#define K_DIM 4096          // D * MERGE^2
#define N_DIM 1024          // D
#define M_TOT 11955         // total merged blocks

#define BM 128
#define BN 128
#define BK 64
#define NWG_M 94            // ceil(11955/128)
#define NWG 752             // (N_DIM/BN) * NWG_M = 8*94, divisible by 8 XCDs
#define KT_TOT 64           // 4 segs x 16 K-steps of 64

// Per-image tables: h = H/14, w = W/14; wm = w/2
__constant__ int c_wm[6]     = {44, 55, 45, 55, 32, 55};
__constant__ int c_w[6]      = {88, 110, 90, 110, 64, 110};
__constant__ int c_tokoff[6] = {0, 9680, 18480, 24240, 36340, 42100};
__constant__ int c_blkoff[6] = {0, 2420, 4620, 6060, 9085, 10525};

typedef __attribute__((ext_vector_type(8))) short bf16x8;
typedef __attribute__((ext_vector_type(4))) float f32x4;

// ---------------------------------------------------------------------------
// Weight fp32 -> bf16 with K-permutation k' = seg*1024 + d where original
// k = 4d + seg (seg = 2*kh + kw). Wp[n, seg*1024+d] = W[n, 4d+seg].
// ---------------------------------------------------------------------------
__global__ __launch_bounds__(256) void wperm_cvt(
    const float* __restrict__ src, __hip_bfloat16* __restrict__ dst)
{
    const int n = blockIdx.x >> 1;
    const int t = (blockIdx.x & 1) * 256 + threadIdx.x;   // 0..511
    const float* row = src + (size_t)n * K_DIM + t * 8;
    float4 a = *(const float4*)row;        // k = 8t..8t+3  (d = 2t)
    float4 b = *(const float4*)(row + 4);  // k = 8t+4..8t+7 (d = 2t+1)
    const float va[8] = {a.x, a.y, a.z, a.w, b.x, b.y, b.z, b.w};
    __hip_bfloat16* drow = dst + (size_t)n * K_DIM + 2 * t;
#pragma unroll
    for (int seg = 0; seg < 4; ++seg) {
        __hip_bfloat162 h = __float22bfloat162_rn(
            make_float2(va[seg], va[4 + seg]));
        *(__hip_bfloat162*)(drow + seg * 1024) = h;
    }
}

// ---------------------------------------------------------------------------
// Fused GEMM, 2-stage software pipeline (T3-minimum):
//   per K-step kt: issue A(kt+1) fp32 global->reg loads, issue B(kt+1)
//   global_load_lds into buf^1, THEN ds_read+MFMA on buf, THEN cvt A regs ->
//   bf16 ds_write into buf^1 (vmcnt wait for A lands after the MFMA cover),
//   then one __syncthreads (drains B DMA) and flip.
// A'[m, seg*1024+d] = feat[tok(m,seg)*1024 + d], read fp32, LDS holds bf16.
// XOR chunk swizzle: LDS slot p of row holds global chunk g = p ^ (row&7)
// (DMA/ds_write dest linear in slot, SOURCE pre-swizzled) -> conflict-free
// ds_read_b128 fragments. 128x128 tile, BK=64, 4 waves, 16x16x32 bf16 MFMA.
// Grid: bijective XCD-chunked swizzle (752 = 8*94) for A-panel L2 locality.
// ---------------------------------------------------------------------------
__global__ __launch_bounds__(256) void gemm_fused(
    const float* __restrict__ A,            // feat fp32 [47820 x 1024]
    const __hip_bfloat16* __restrict__ Wp,  // permuted weight bf16 [1024 x 4096]
    float* __restrict__ C)
{
    __shared__ __align__(16) __hip_bfloat16 lA[2][BM * BK]; // 2 x 16 KB
    __shared__ __align__(16) __hip_bfloat16 lB[2][BN * BK]; // 2 x 16 KB

    // ---- XCD-chunked swizzle (bijective)
    const int f    = blockIdx.x;
    const int xcd  = f & 7;
    const int slot = f >> 3;                 // 0..93
    const int gidx = xcd * NWG_M + slot;
    const int mt   = gidx >> 3;              // 0..93
    const int nt   = gidx & 7;               // 0..7
    const int m0 = mt * BM;
    const int n0 = nt * BN;

    const int tid  = threadIdx.x;
    const int lane = tid & 63;
    const int wave = tid >> 6;
    const int wm = (wave >> 1) * 64;
    const int wn = (wave & 1) * 64;
    const int al = lane & 15;
    const int q  = lane >> 4;
    const int al7 = al & 7;

    // ---- staging descriptors: chunk c = tid + j*256, row = c>>3,
    // LDS slot p = c&7 holds global chunk g = p ^ (row&7).
    int t00[4], wwA[4];
    const __hip_bfloat16* pBbase[4];
#pragma unroll
    for (int j = 0; j < 4; ++j) {
        const int c = tid + j * 256;
        const int row = c >> 3;
        const int g = (c & 7) ^ (row & 7);
        int gm = m0 + row; if (gm > M_TOT - 1) gm = M_TOT - 1;
        int img = 0;
#pragma unroll
        for (int u = 1; u < 6; ++u) if (gm >= c_blkoff[u]) img = u;
        const int bi = gm - c_blkoff[img];
        const int wmrg = c_wm[img];
        const int gi = bi / wmrg;
        const int gj = bi - gi * wmrg;
        const int w = c_w[img];
        t00[j] = c_tokoff[img] + 2 * gi * w + 2 * gj;   // token of (kh,kw)=(0,0)
        pBbase[j] = Wp + (size_t)(n0 + row) * K_DIM + g * 8;
        wwA[j] = w | (g << 16);
    }

    // per-tile address helpers (kt -> seg, k2)
    auto aptr = [&](int j, int kt) -> const float* {
        const int seg = kt >> 4;
        const int k2  = (kt & 15) * BK;
        const int kh = seg >> 1, kw = seg & 1;
        const int w = wwA[j] & 0xffff;
        const int g = wwA[j] >> 16;
        return A + (size_t)(t00[j] + (kh ? w : 0) + kw) * N_DIM + g * 8 + k2;
    };
    auto bptr = [&](int j, int kt) -> const __hip_bfloat16* {
        const int seg = kt >> 4;
        const int k2  = (kt & 15) * BK;
        return pBbase[j] + seg * 1024 + k2;
    };

    // ---- prologue: stage tile 0 into buffer 0
    {
        float4 ra[4][2];
#pragma unroll
        for (int j = 0; j < 4; ++j) {
            const float4* s = (const float4*)aptr(j, 0);
            ra[j][0] = s[0]; ra[j][1] = s[1];
        }
#pragma unroll
        for (int j = 0; j < 4; ++j)
            __builtin_amdgcn_global_load_lds(
                (const __attribute__((address_space(1))) void*)bptr(j, 0),
                (__attribute__((address_space(3))) void*)(&lB[0][0] + (tid + j * 256) * 8),
                16, 0, 0);
#pragma unroll
        for (int j = 0; j < 4; ++j) {
            union { __hip_bfloat162 h2[4]; uint4 u; } pk;
            pk.h2[0] = __float22bfloat162_rn(make_float2(ra[j][0].x, ra[j][0].y));
            pk.h2[1] = __float22bfloat162_rn(make_float2(ra[j][0].z, ra[j][0].w));
            pk.h2[2] = __float22bfloat162_rn(make_float2(ra[j][1].x, ra[j][1].y));
            pk.h2[3] = __float22bfloat162_rn(make_float2(ra[j][1].z, ra[j][1].w));
            *(uint4*)(&lA[0][0] + (tid + j * 256) * 8) = pk.u;
        }
        __syncthreads();
    }

    f32x4 acc[4][4];
#pragma unroll
    for (int i = 0; i < 4; ++i)
#pragma unroll
        for (int j = 0; j < 4; ++j)
            acc[i][j] = (f32x4){0.f, 0.f, 0.f, 0.f};

    for (int kt = 0; kt < KT_TOT; ++kt) {
        const int cur = kt & 1;
        const int nxt = cur ^ 1;
        const bool more = (kt + 1 < KT_TOT);

        // ---- issue next tile's loads FIRST (fire-and-forget)
        float4 ra[4][2];
        if (more) {
#pragma unroll
            for (int j = 0; j < 4; ++j) {
                const float4* s = (const float4*)aptr(j, kt + 1);
                ra[j][0] = s[0]; ra[j][1] = s[1];
            }
#pragma unroll
            for (int j = 0; j < 4; ++j)
                __builtin_amdgcn_global_load_lds(
                    (const __attribute__((address_space(1))) void*)bptr(j, kt + 1),
                    (__attribute__((address_space(3))) void*)(&lB[nxt][0] + (tid + j * 256) * 8),
                    16, 0, 0);
        }

        // ---- compute on current buffer (covers the in-flight loads)
        const __hip_bfloat16* la = &lA[cur][0];
        const __hip_bfloat16* lb = &lB[cur][0];
        bf16x8 af[4], bfr[4];
#pragma unroll
        for (int ks = 0; ks < 2; ++ks) {
#pragma unroll
            for (int mi = 0; mi < 4; ++mi) {
                const int r = wm + mi * 16 + al;
                const int p = (ks * 4 + q) ^ al7;
                af[mi] = *(const bf16x8*)(la + r * BK + p * 8);
            }
#pragma unroll
            for (int ni = 0; ni < 4; ++ni) {
                const int r = wn + ni * 16 + al;
                const int p = (ks * 4 + q) ^ al7;
                bfr[ni] = *(const bf16x8*)(lb + r * BK + p * 8);
            }
#pragma unroll
            for (int mi = 0; mi < 4; ++mi)
#pragma unroll
                for (int ni = 0; ni < 4; ++ni)
                    acc[mi][ni] = __builtin_amdgcn_mfma_f32_16x16x32_bf16(
                        af[mi], bfr[ni], acc[mi][ni], 0, 0, 0);
        }

        // ---- A: cvt + swizzled ds_write into next buffer (waits A vmcnt here)
        if (more) {
#pragma unroll
            for (int j = 0; j < 4; ++j) {
                union { __hip_bfloat162 h2[4]; uint4 u; } pk;
                pk.h2[0] = __float22bfloat162_rn(make_float2(ra[j][0].x, ra[j][0].y));
                pk.h2[1] = __float22bfloat162_rn(make_float2(ra[j][0].z, ra[j][0].w));
                pk.h2[2] = __float22bfloat162_rn(make_float2(ra[j][1].x, ra[j][1].y));
                pk.h2[3] = __float22bfloat162_rn(make_float2(ra[j][1].z, ra[j][1].w));
                *(uint4*)(&lA[nxt][0] + (tid + j * 256) * 8) = pk.u;
            }
        }
        __syncthreads();   // drains B DMA (vmcnt) + A ds_write (lgkm)
    }

    // C/D layout: col = lane&15, row = (lane>>4)*4 + reg
#pragma unroll
    for (int mi = 0; mi < 4; ++mi) {
        const int row = m0 + wm + mi * 16 + q * 4;
#pragma unroll
        for (int ni = 0; ni < 4; ++ni) {
            const int col = n0 + wn + ni * 16 + al;
            float* cp = C + (size_t)row * N_DIM + col;
#pragma unroll
            for (int rg = 0; rg < 4; ++rg) {
                if (row + rg < M_TOT) cp[(size_t)rg * N_DIM] = acc[mi][ni][rg];
            }
        }
    }
}

extern "C" void kernel_launch(void* const* d_in, const int* in_sizes, int n_in,
                              void* d_out, int out_size, void* d_ws, size_t ws_size,
                              hipStream_t stream)
{
    const float* feat = (const float*)d_in[0];
    const float* wgt  = (const float*)d_in[1];
    float* out = (float*)d_out;

    __hip_bfloat16* wp = (__hip_bfloat16*)d_ws;   // 8 MB permuted bf16 weight

    wperm_cvt<<<2048, 256, 0, stream>>>(wgt, wp);
    gemm_fused<<<NWG, 256, 0, stream>>>(feat, wp, out);
}

// Round 5
// 448.633 us; speedup vs baseline: 1.1141x; 1.1141x over previous
//
#include <hip/hip_runtime.h>
#include <hip/hip_bf16.h>
#include <stdint.h>

// Problem constants (IMAGE_SIZES is compile-time constant in the reference)
#define K_DIM 4096          // D * MERGE^2
#define N_DIM 1024          // D
#define M_TOT 11955         // total merged blocks

// GEMM geometry: 256x256 tile, BK=64, 8 waves (2M x 4N), 128 KB LDS dbuf
#define BM 256
#define BN 256
#define BK 64
#define KT_N 64             // K_DIM / BK
#define M_TILES 47          // ceil(11955/256)
#define N_TILES 4           // 1024/256
#define NWG 188             // 47*4

// Per-image tables: h = H/14, w = W/14; wm = w/2
__constant__ int c_wm[6]     = {44, 55, 45, 55, 32, 55};
__constant__ int c_w[6]      = {88, 110, 90, 110, 64, 110};
__constant__ int c_tokoff[6] = {0, 9680, 18480, 24240, 36340, 42100};
__constant__ int c_blkoff[6] = {0, 2420, 4620, 6060, 9085, 10525};

typedef __attribute__((ext_vector_type(8))) short bf16x8;
typedef __attribute__((ext_vector_type(4))) float f32x4;

// raw workgroup barrier: NO automatic vmcnt/lgkmcnt drain (unlike
// __syncthreads), with compiler memory fences to pin ordering.
#define BARRIER() do { asm volatile("" ::: "memory"); \
                       __builtin_amdgcn_s_barrier();  \
                       asm volatile("" ::: "memory"); } while (0)
#define VMCNT0()  asm volatile("s_waitcnt vmcnt(0)" ::: "memory")

// ---------------------------------------------------------------------------
// Weight fp32 -> bf16 with K-permutation k' = seg*1024 + d where original
// k = 4d + seg (seg = 2*kh + kw). Wp[n, seg*1024+d] = W[n, 4d+seg].
// ---------------------------------------------------------------------------
__global__ __launch_bounds__(256) void wperm_cvt(
    const float* __restrict__ src, __hip_bfloat16* __restrict__ dst)
{
    const int n = blockIdx.x >> 1;
    const int t = (blockIdx.x & 1) * 256 + threadIdx.x;   // 0..511
    const float* row = src + (size_t)n * K_DIM + t * 8;
    float4 a = *(const float4*)row;        // k = 8t..8t+3  (d = 2t)
    float4 b = *(const float4*)(row + 4);  // k = 8t+4..8t+7 (d = 2t+1)
    const float va[8] = {a.x, a.y, a.z, a.w, b.x, b.y, b.z, b.w};
    __hip_bfloat16* drow = dst + (size_t)n * K_DIM + 2 * t;
#pragma unroll
    for (int seg = 0; seg < 4; ++seg) {
        __hip_bfloat162 h = __float22bfloat162_rn(
            make_float2(va[seg], va[4 + seg]));
        *(__hip_bfloat162*)(drow + seg * 1024) = h;
    }
}

// ---------------------------------------------------------------------------
// Unfold + cvt: Am[m, seg*1024+d] = bf16(feat[tok(m,seg)*1024 + d]).
// One block per merged row: 4x 4KB contiguous reads, one 8KB contiguous
// write. After this, the GEMM is a plain dense [M x 4096] @ [1024 x 4096]^T.
// ---------------------------------------------------------------------------
__global__ __launch_bounds__(256) void unfold_cvt(
    const float* __restrict__ feat, __hip_bfloat16* __restrict__ Am)
{
    const int m = blockIdx.x;            // 0..M_TOT-1
    const int t = threadIdx.x;           // 0..255
    const int seg = t >> 6;              // 0..3
    const int d0 = (t & 63) * 16;        // 0..1008
    int img = 0;
#pragma unroll
    for (int u = 1; u < 6; ++u) if (m >= c_blkoff[u]) img = u;
    const int bi = m - c_blkoff[img];
    const int wmrg = c_wm[img];
    const int gi = bi / wmrg;
    const int gj = bi - gi * wmrg;
    const int w  = c_w[img];
    const int kh = seg >> 1, kw = seg & 1;
    const int tok = c_tokoff[img] + 2 * gi * w + 2 * gj + kh * w + kw;
    const float4* src = (const float4*)(feat + (size_t)tok * N_DIM + d0);
    float4 v0 = src[0], v1 = src[1], v2 = src[2], v3 = src[3];
    union { __hip_bfloat162 h[8]; uint4 u4[2]; } pk;
    pk.h[0] = __float22bfloat162_rn(make_float2(v0.x, v0.y));
    pk.h[1] = __float22bfloat162_rn(make_float2(v0.z, v0.w));
    pk.h[2] = __float22bfloat162_rn(make_float2(v1.x, v1.y));
    pk.h[3] = __float22bfloat162_rn(make_float2(v1.z, v1.w));
    pk.h[4] = __float22bfloat162_rn(make_float2(v2.x, v2.y));
    pk.h[5] = __float22bfloat162_rn(make_float2(v2.z, v2.w));
    pk.h[6] = __float22bfloat162_rn(make_float2(v3.x, v3.y));
    pk.h[7] = __float22bfloat162_rn(make_float2(v3.z, v3.w));
    uint4* dst = (uint4*)(Am + (size_t)m * K_DIM + seg * 1024 + d0);
    dst[0] = pk.u4[0];
    dst[1] = pk.u4[1];
}

// ---------------------------------------------------------------------------
// Dense bf16 GEMM, 256x256 tile, 8 waves, 4-phase-per-K-tile pipelined
// schedule (T2 swizzle + T3/T4 counted-drain + T5 setprio):
//   phase p: {ds_read frags (B:8 + A:4 at p0, A:4 else) |
//             issue 4 global_load_lds for tile kt+1 (A @ p0, B @ p1)}
//            raw barrier; setprio(1); 16 MFMA (C-quadrant p); setprio(0);
//            [p3: s_waitcnt vmcnt(0)]; raw barrier.
// vmcnt(0) once per K-tile AFTER 3 phases of compute cover (~1000 cyc) --
// unlike __syncthreads' drain-at-issue. Raw barriers carry no waitcnt; the
// only cross-wave hazard (DMA-written LDS) is published by the per-tile
// vmcnt+barrier. XOR-8 chunk swizzle (slot p holds chunk g = p ^ (row&7),
// DMA dest linear / source pre-swizzled) keeps ds_read_b128 conflict-free.
// Grid: 188 WGs, bijective XCD-chunked swizzle, n-tile fastest in-chunk.
// ---------------------------------------------------------------------------
__global__ __launch_bounds__(512, 2) void gemm8(
    const __hip_bfloat16* __restrict__ Am,  // [M_TOT x 4096] merged bf16
    const __hip_bfloat16* __restrict__ Wp,  // [1024 x 4096] permuted bf16
    float* __restrict__ C)
{
    __shared__ __align__(16) __hip_bfloat16 lA[2][BM * BK]; // 64 KB
    __shared__ __align__(16) __hip_bfloat16 lB[2][BN * BK]; // 64 KB

    // ---- bijective XCD-chunked swizzle for 188 = 8*23 + 4:
    // xcd x<4 gets 24 slots, else 23; n-tile fastest within a chunk.
    const int orig = blockIdx.x;
    const int x    = orig & 7;
    const int idx  = orig >> 3;
    const int start = (x < 4) ? x * 24 : 96 + (x - 4) * 23;
    const int wgid  = start + idx;
    const int mt = wgid >> 2;               // 0..46
    const int nt = wgid & 3;                // 0..3
    const int m0 = mt * BM;
    const int n0 = nt * BN;

    const int tid  = threadIdx.x;           // 0..511
    const int lane = tid & 63;
    const int wave = tid >> 6;              // 0..7
    const int wm = (wave >> 2) * 128;       // 0 or 128
    const int wn = (wave & 3) * 64;         // 0,64,128,192
    const int al = lane & 15;
    const int q  = lane >> 4;
    const int al7 = al & 7;

    // ---- staging descriptors: 2048 chunks of 16B per operand tile,
    // 4 per thread. chunk c = tid + i*512: row = c>>3, slot = c&7 holds
    // global chunk g = slot ^ (row&7). LDS dest linear, source swizzled.
    const __hip_bfloat16* srcA[4];
    const __hip_bfloat16* srcB[4];
#pragma unroll
    for (int i = 0; i < 4; ++i) {
        const int c = tid + i * 512;
        const int r = c >> 3;
        const int g = (c & 7) ^ (r & 7);
        int gm = m0 + r; if (gm > M_TOT - 1) gm = M_TOT - 1;  // clamp tail
        srcA[i] = Am + (size_t)gm * K_DIM + g * 8;
        srcB[i] = Wp + (size_t)(n0 + r) * K_DIM + g * 8;
    }

    // ---- prologue: stage tile 0 into buffer 0, full drain once
#pragma unroll
    for (int i = 0; i < 4; ++i)
        __builtin_amdgcn_global_load_lds(
            (const __attribute__((address_space(1))) void*)srcA[i],
            (__attribute__((address_space(3))) void*)(&lA[0][0] + (tid + i * 512) * 8),
            16, 0, 0);
#pragma unroll
    for (int i = 0; i < 4; ++i)
        __builtin_amdgcn_global_load_lds(
            (const __attribute__((address_space(1))) void*)srcB[i],
            (__attribute__((address_space(3))) void*)(&lB[0][0] + (tid + i * 512) * 8),
            16, 0, 0);
    __syncthreads();   // vmcnt(0)+barrier: tile 0 visible to all waves

    f32x4 acc[8][4];
#pragma unroll
    for (int i = 0; i < 8; ++i)
#pragma unroll
        for (int j = 0; j < 4; ++j)
            acc[i][j] = (f32x4){0.f, 0.f, 0.f, 0.f};

    for (int kt = 0; kt < KT_N; ++kt) {
        const int cur = kt & 1;
        const __hip_bfloat16* la = &lA[cur][0];
        const __hip_bfloat16* lb = &lB[cur][0];
        __hip_bfloat16* wa = &lA[cur ^ 1][0];
        __hip_bfloat16* wb = &lB[cur ^ 1][0];
        const bool more = (kt + 1 < KT_N);
        const int koff = (kt + 1) * BK;     // next tile's k offset (elems)

        bf16x8 bfr[4][2];
#pragma unroll
        for (int p = 0; p < 4; ++p) {
            // ---- fragment ds_reads for this phase
            if (p == 0) {
#pragma unroll
                for (int ks = 0; ks < 2; ++ks)
#pragma unroll
                    for (int ni = 0; ni < 4; ++ni) {
                        const int r = wn + ni * 16 + al;
                        bfr[ni][ks] = *(const bf16x8*)(
                            lb + r * BK + (((ks * 4 + q) ^ al7) * 8));
                    }
            }
            bf16x8 af[2][2];
#pragma unroll
            for (int ks = 0; ks < 2; ++ks)
#pragma unroll
                for (int mm = 0; mm < 2; ++mm) {
                    const int r = wm + (p * 2 + mm) * 16 + al;
                    af[mm][ks] = *(const bf16x8*)(
                        la + r * BK + (((ks * 4 + q) ^ al7) * 8));
                }
            // ---- prefetch issues for tile kt+1 (fire-and-forget)
            if (p == 0 && more) {
#pragma unroll
                for (int i = 0; i < 4; ++i)
                    __builtin_amdgcn_global_load_lds(
                        (const __attribute__((address_space(1))) void*)(srcA[i] + koff),
                        (__attribute__((address_space(3))) void*)(wa + (tid + i * 512) * 8),
                        16, 0, 0);
            }
            if (p == 1 && more) {
#pragma unroll
                for (int i = 0; i < 4; ++i)
                    __builtin_amdgcn_global_load_lds(
                        (const __attribute__((address_space(1))) void*)(srcB[i] + koff),
                        (__attribute__((address_space(3))) void*)(wb + (tid + i * 512) * 8),
                        16, 0, 0);
            }
            BARRIER();
            __builtin_amdgcn_s_setprio(1);
#pragma unroll
            for (int ks = 0; ks < 2; ++ks)
#pragma unroll
                for (int mm = 0; mm < 2; ++mm)
#pragma unroll
                    for (int ni = 0; ni < 4; ++ni)
                        acc[p * 2 + mm][ni] = __builtin_amdgcn_mfma_f32_16x16x32_bf16(
                            af[mm][ks], bfr[ni][ks], acc[p * 2 + mm][ni], 0, 0, 0);
            __builtin_amdgcn_s_setprio(0);
            if (p == 3) VMCNT0();   // publish tile kt+1 (covered by 3 phases)
            BARRIER();
        }
    }

    // ---- C epilogue. C/D layout: col = lane&15, row = (lane>>4)*4 + reg
#pragma unroll
    for (int mi = 0; mi < 8; ++mi) {
        const int row = m0 + wm + mi * 16 + q * 4;
#pragma unroll
        for (int ni = 0; ni < 4; ++ni) {
            const int col = n0 + wn + ni * 16 + al;
            float* cp = C + (size_t)row * N_DIM + col;
#pragma unroll
            for (int rg = 0; rg < 4; ++rg) {
                if (row + rg < M_TOT) cp[(size_t)rg * N_DIM] = acc[mi][ni][rg];
            }
        }
    }
}

extern "C" void kernel_launch(void* const* d_in, const int* in_sizes, int n_in,
                              void* d_out, int out_size, void* d_ws, size_t ws_size,
                              hipStream_t stream)
{
    const float* feat = (const float*)d_in[0];
    const float* wgt  = (const float*)d_in[1];
    float* out = (float*)d_out;

    __hip_bfloat16* Am = (__hip_bfloat16*)d_ws;                 // 98 MB
    __hip_bfloat16* wp = (__hip_bfloat16*)((char*)d_ws +
                         (size_t)M_TOT * K_DIM * sizeof(__hip_bfloat16)); // +8 MB

    wperm_cvt<<<2048, 256, 0, stream>>>(wgt, wp);
    unfold_cvt<<<M_TOT, 256, 0, stream>>>(feat, Am);
    gemm8<<<NWG, 512, 0, stream>>>(Am, wp, out);
}